// Round 1
// 1334.815 us; speedup vs baseline: 1.0346x; 1.0346x over previous
//
#include <hip/hip_runtime.h>
#include <math.h>

#define NROWS 8192
#define VDIM  32000
#define V4    (VDIM / 4)
#define LOG_V 10.373491181781864f   // ln(32000)

// Combine two online-softmax partials (max m, second-max l2, s=sum exp(x-m),
// t=sum exp(x-m)*(x-m)).
__device__ __forceinline__ void sm_combine(float &m, float &l2, float &s, float &t,
                                           float m2, float l22, float s2, float t2) {
    float M  = fmaxf(m, m2);
    float L2 = fmaxf(fminf(m, m2), fmaxf(l2, l22));
    float c1 = __expf(m  - M);
    float c2 = __expf(m2 - M);
    float T  = c1 * (t + s * (m - M)) + c2 * (t2 + s2 * (m2 - M));
    float S  = c1 * s + c2 * s2;
    m = M; l2 = L2; s = S; t = T;
}

// One block per row: single-pass online softmax stats.
// 4-deep load unroll: same element ORDER as the reference loop (i, i+256, ...)
// so accumulation is bit-identical; just issues 4 independent float4 loads
// before the dependent exp/branch chain consumes them.
__global__ __launch_bounds__(256) void row_stats_kernel(
    const float* __restrict__ logits, const int* __restrict__ targets,
    float* __restrict__ ce_out, float* __restrict__ dp_out,
    float* __restrict__ conf_out)
{
    const int r   = blockIdx.x;
    const int tid = threadIdx.x;
    const float4* row = reinterpret_cast<const float4*>(logits + (size_t)r * VDIM);

    // -1e30 sentinel: finite so rescale math (s*(m-x)) stays 0*finite = 0, no NaN.
    float m = -1e30f, l2 = -1e30f, s = 0.0f, t = 0.0f;

    auto proc = [&](float4 v) {
        float xs[4] = {v.x, v.y, v.z, v.w};
#pragma unroll
        for (int j = 0; j < 4; ++j) {
            float x = xs[j];
            if (x > m) {                    // rare: new running max, rescale
                float c = __expf(m - x);
                t = (t + s * (m - x)) * c;
                s = fmaf(s, c, 1.0f);
                l2 = m;
                m = x;
            } else {                        // common path: 5 VALU + 1 trans
                float d = __expf(x - m);
                l2 = fmaxf(l2, x);
                s += d;
                t = fmaf(d, x - m, t);
            }
        }
    };

    int i = tid;
    for (; i + 768 < V4; i += 1024) {
        float4 a = row[i];
        float4 b = row[i + 256];
        float4 c = row[i + 512];
        float4 d = row[i + 768];
        proc(a); proc(b); proc(c); proc(d);
    }
    for (; i < V4; i += 256) proc(row[i]);

    // wave-64 butterfly reduction
#pragma unroll
    for (int mask = 1; mask < 64; mask <<= 1) {
        float m2  = __shfl_xor(m,  mask, 64);
        float l22 = __shfl_xor(l2, mask, 64);
        float s2  = __shfl_xor(s,  mask, 64);
        float t2  = __shfl_xor(t,  mask, 64);
        sm_combine(m, l2, s, t, m2, l22, s2, t2);
    }

    __shared__ float red[4][4];
    const int wave = tid >> 6;
    const int lane = tid & 63;
    if (lane == 0) { red[wave][0] = m; red[wave][1] = l2; red[wave][2] = s; red[wave][3] = t; }
    __syncthreads();
    if (tid == 0) {
        for (int w = 1; w < 4; ++w)
            sm_combine(m, l2, s, t, red[w][0], red[w][1], red[w][2], red[w][3]);
        float lt    = logits[(size_t)r * VDIM + targets[r]];
        float logs  = __logf(s);
        float inv_s = 1.0f / s;
        float ce     = (m - lt) + logs;               // -logp[target]
        float ent    = logs - t * inv_s;              // -sum p*logp
        float conf   = inv_s;                         // p_max = exp(m-m)/s
        float margin = (1.0f - __expf(l2 - m)) * inv_s;
        ce_out[r]   = ce;
        dp_out[r]   = ent * (1.0f / LOG_V) + (1.0f - margin);  // difficulty sans loss_norm
        conf_out[r] = conf;
    }
}

// Single-block finalize: global reductions, exact radix-select for the k-th
// largest difficulty (replaces 91-pass bitonic sort), masked CE mean.
//
// Keys: monotonic bijection float -> uint32 (u = sign ? ~u : u|0x80000000).
// Selecting in key space gives the exact same selected SET as the reference's
// `d >= sorted_d[N-k]` (ties included), since the transform is order-preserving
// and all difficulties are non-negative sums (no -0.0 possible).
__global__ __launch_bounds__(1024) void finalize_kernel(
    const float* __restrict__ ce_arr, const float* __restrict__ dp_arr,
    const float* __restrict__ conf_arr, const int* __restrict__ step_count,
    float* __restrict__ out)
{
    __shared__ unsigned keys[NROWS];     // 32 KB
    __shared__ float    s_ce[NROWS];     // 32 KB
    __shared__ unsigned hist[256];       // 1 KB
    __shared__ float wredA[16], wredB[16];
    __shared__ float s_bc[2];            // [0]=max_ce+1e-6, [1]=avg_conf
    __shared__ unsigned s_prefix;
    __shared__ int s_krem;

    const int tid  = threadIdx.x;
    const int wave = tid >> 6;
    const int lane = tid & 63;

    // pass 1: stage ce into LDS; reduce max(ce), sum(conf)
    float mx = -1e30f, sc = 0.0f;
    for (int i = tid; i < NROWS; i += 1024) {
        float ce = ce_arr[i];
        s_ce[i] = ce;
        mx = fmaxf(mx, ce);
        sc += conf_arr[i];
    }
#pragma unroll
    for (int msk = 1; msk < 64; msk <<= 1) {
        mx = fmaxf(mx, __shfl_xor(mx, msk, 64));
        sc += __shfl_xor(sc, msk, 64);
    }
    if (lane == 0) { wredA[wave] = mx; wredB[wave] = sc; }
    __syncthreads();
    if (tid == 0) {
        float M = wredA[0], S = wredB[0];
        for (int w = 1; w < 16; ++w) { M = fmaxf(M, wredA[w]); S += wredB[w]; }
        s_bc[0] = M + 1e-6f;
        s_bc[1] = S * (1.0f / (float)NROWS);
    }
    __syncthreads();
    const float denom = s_bc[0];

    // pass 2: difficulty -> order-preserving uint key, into LDS
    for (int i = tid; i < NROWS; i += 1024) {
        float d = (dp_arr[i] + s_ce[i] / denom) * (1.0f / 3.0f);
        unsigned u = __float_as_uint(d);
        keys[i] = (u & 0x80000000u) ? ~u : (u | 0x80000000u);
    }
    if (tid == 0) {
        float progress   = fminf(1.0f, (float)step_count[0] * (1.0f / 1000.0f));
        float base_ratio = 1.0f - progress * 0.75f;   // 1 - progress*(1-0.25)
        float avg_conf   = s_bc[1];
        float ratio = base_ratio * (1.0f + 0.5f * (0.5f - avg_conf) * 2.0f);
        ratio = fminf(fmaxf(ratio, 0.01f), 1.0f);
        int kk = (int)rintf(ratio * (float)NROWS);    // rint = round-half-even (jnp.round)
        kk = kk < 1 ? 1 : (kk > NROWS ? NROWS : kk);
        s_krem = kk;
        s_prefix = 0u;
    }
    __syncthreads();

    // radix select: 4 MSB-first 8-bit passes -> exact k-th largest key
    unsigned hi_mask = 0u;
#pragma unroll
    for (int shift = 24; shift >= 0; shift -= 8) {
        if (tid < 256) hist[tid] = 0u;
        __syncthreads();
        const unsigned pfx = s_prefix;
        for (int i = tid; i < NROWS; i += 1024) {
            unsigned u = keys[i];
            if ((u & hi_mask) == pfx)
                atomicAdd(&hist[(u >> shift) & 255u], 1u);
        }
        __syncthreads();
        if (tid == 0) {
            // branchless full scan from the top bin (no early break -> the
            // compiler can pipeline the 256 LDS reads instead of serializing
            // on a dependent break condition)
            int krem = s_krem;
            unsigned c = 0;
            int sel = -1;
            int rem = 0;
            for (int b = 255; b >= 0; --b) {
                unsigned h = hist[b];
                unsigned cnew = c + h;
                bool hit = ((int)cnew >= krem) && (sel < 0);
                if (hit) { sel = b; rem = krem - (int)c; }   // c = count of strictly-higher bins
                c = cnew;
            }
            s_krem   = rem;
            s_prefix = pfx | ((unsigned)sel << shift);
        }
        __syncthreads();
        hi_mask |= (0xFFu << shift);
    }
    const unsigned kth = s_prefix;

    // pass 3: masked CE sum via key-space compare (same set as d >= threshold)
    float msum = 0.0f, mcnt = 0.0f;
    for (int i = tid; i < NROWS; i += 1024) {
        if (keys[i] >= kth) { msum += s_ce[i]; mcnt += 1.0f; }
    }
#pragma unroll
    for (int msk = 1; msk < 64; msk <<= 1) {
        msum += __shfl_xor(msum, msk, 64);
        mcnt += __shfl_xor(mcnt, msk, 64);
    }
    __syncthreads();   // wred arrays reused
    if (lane == 0) { wredA[wave] = msum; wredB[wave] = mcnt; }
    __syncthreads();
    if (tid == 0) {
        float S = 0.0f, C = 0.0f;
        for (int w = 0; w < 16; ++w) { S += wredA[w]; C += wredB[w]; }
        out[0] = S / fmaxf(C, 1.0f);
    }
}

extern "C" void kernel_launch(void* const* d_in, const int* in_sizes, int n_in,
                              void* d_out, int out_size, void* d_ws, size_t ws_size,
                              hipStream_t stream) {
    const float* logits  = (const float*)d_in[0];
    const int*   targets = (const int*)d_in[1];
    const int*   step    = (const int*)d_in[2];
    float* ws = (float*)d_ws;
    float* ce = ws;
    float* dp = ws + NROWS;
    float* cf = ws + 2 * NROWS;

    row_stats_kernel<<<NROWS, 256, 0, stream>>>(logits, targets, ce, dp, cf);
    finalize_kernel<<<1, 1024, 0, stream>>>(ce, dp, cf, step, (float*)d_out);
}